// Round 16
// baseline (367.678 us; speedup 1.0000x reference)
//
#include <hip/hip_runtime.h>
#include <stdint.h>

// ---------------------------------------------------------------------------
// EfficientVIM block, MI355X. Dims: B=16, C=256, H=W=64, L=4096, S=64,
// CONV_DIM=192, HID=1024. All GEMMs via mfma_f32_16x16x32_bf16 (fp32 accum).
// R16: T2 bank-conflict fix for ffn1/ffn2 via BOTH-sides swizzle (rule #21):
// producers (k_setup w1b/w2b, k_xt x3T, ffn1 H-write) store columns XOR-
// swizzled within 64-col blocks keyed by (row&7)<<3; ffn1/ffn2 fragment
// reads apply the same XOR. Kills the 16-way ds_read conflict (9.4M cycles
// in ffn2 = ~15us/CU). Everything else = R15 (best, 359.0us).
// ---------------------------------------------------------------------------

typedef __attribute__((ext_vector_type(8))) short bf16x8;
typedef __attribute__((ext_vector_type(4))) float f32x4;

__device__ __forceinline__ unsigned short f2b(float f){
  union { float f; unsigned int u; } v; v.f = f;
  unsigned int r = v.u + 0x7FFFu + ((v.u >> 16) & 1u);   // RNE
  return (unsigned short)(r >> 16);
}
__device__ __forceinline__ float b2f(unsigned short h){
  union { unsigned int u; float f; } v; v.u = ((unsigned int)h) << 16;
  return v.f;
}
__device__ __forceinline__ float sigm(float x){ return 1.0f / (1.0f + __expf(-x)); }
// tanh-approx gelu in sigmoid form: v * sigmoid(2u), 2u*log2e folded in.
__device__ __forceinline__ float gelu_fast(float v){
  float t = v * (-2.3022059f - 0.10294886f * v * v);
  float e = __builtin_amdgcn_exp2f(t);
  return v * __builtin_amdgcn_rcpf(1.0f + e);
}
__device__ __forceinline__ unsigned int cvtpk(float lo, float hi){
  unsigned int r;
  asm volatile("v_cvt_pk_bf16_f32 %0, %1, %2" : "=v"(r) : "v"(lo), "v"(hi));
  return r;
}
__device__ __forceinline__ f32x4 mfma16(bf16x8 a, bf16x8 b, f32x4 c){
  return __builtin_amdgcn_mfma_f32_16x16x32_bf16(a, b, c, 0, 0, 0);
}
__device__ __forceinline__ bf16x8 ldb8g(const unsigned short* p){
  return *reinterpret_cast<const bf16x8*>(p);
}
__device__ __forceinline__ f32x4 zero4(){ f32x4 v = {0.f, 0.f, 0.f, 0.f}; return v; }
__device__ __forceinline__ void gload_lds16(const unsigned short* g, unsigned short* l){
  __builtin_amdgcn_global_load_lds(
      (const __attribute__((address_space(1))) void*)g,
      (__attribute__((address_space(3))) void*)l, 16, 0, 0);
}

// ---------------------------------------------------------------------------
// K0: weight conversion. w1b/w2b stored COLUMN-SWIZZLED within 64-col blocks:
// wXb[o][c] = wX[o][c ^ ((o&7)<<3)]  (involution, granule-preserving).
__global__ __launch_bounds__(256) void k_setup(
    const float* __restrict__ w1, const float* __restrict__ w2,
    const float* __restrict__ bw, const float* __restrict__ hzw,
    const float* __restrict__ outw,
    unsigned short* __restrict__ w1b, unsigned short* __restrict__ w2b,
    unsigned short* __restrict__ bwb, unsigned short* __restrict__ hzwb,
    unsigned short* __restrict__ outwb){
  int tid = blockIdx.x * 256 + threadIdx.x;          // grid 1024 -> 262144
  if (tid < 1024 * 256){
    // w1: [1024 o][256 c]
    int o1 = tid >> 8, c1 = tid & 255;
    int c1s = c1 ^ ((o1 & 7) << 3);
    w1b[tid] = f2b(w1[(size_t)o1 * 256 + c1s]);
    // w2: [256 o][1024 c]
    int o2 = tid >> 10, c2 = tid & 1023;
    int c2s = c2 ^ ((o2 & 7) << 3);
    w2b[tid] = f2b(w2[(size_t)o2 * 1024 + c2s]);
  }
  if (tid < 192 * 256)  bwb[tid] = f2b(bw[tid]);
  if (tid < 512 * 256)  hzwb[tid] = f2b(hzw[tid]);
  if (tid < 256 * 256)  outwb[tid] = f2b(outw[tid]);
}

// ---------------------------------------------------------------------------
// K1: depthwise 3x3 conv (zero pad), fp32 input -> per-channel sum/sumsq
__global__ __launch_bounds__(256) void k_conv_stats(
    const float* __restrict__ x, const float* __restrict__ w,
    float* __restrict__ bnsum, float* __restrict__ bnsq){
  __shared__ float t[66 * 66];
  __shared__ float rs[4], rq[4];
  int bc = blockIdx.x; int c = bc & 255;
  const float* xp = x + (size_t)bc * 4096;
  int tid = threadIdx.x;
  for (int i = tid; i < 66 * 66; i += 256) t[i] = 0.f;
  __syncthreads();
  #pragma unroll
  for (int j = 0; j < 4; j++){
    int p4 = tid + j * 256;
    float4 v = reinterpret_cast<const float4*>(xp)[p4];
    int p = p4 * 4; int y = p >> 6, xx = p & 63;
    int base = (y + 1) * 66 + xx + 1;
    t[base] = v.x; t[base + 1] = v.y; t[base + 2] = v.z; t[base + 3] = v.w;
  }
  __syncthreads();
  float w0 = w[c*9+0], w1 = w[c*9+1], w2 = w[c*9+2], w3 = w[c*9+3], w4 = w[c*9+4];
  float w5 = w[c*9+5], w6 = w[c*9+6], w7 = w[c*9+7], w8 = w[c*9+8];
  float s = 0.f, q = 0.f;
  #pragma unroll
  for (int j = 0; j < 16; j++){
    int p = tid + j * 256; int y = p >> 6, xx = p & 63;
    const float* r0 = &t[y * 66 + xx];
    float v = r0[0]*w0 + r0[1]*w1 + r0[2]*w2 + r0[66]*w3 + r0[67]*w4 + r0[68]*w5
            + r0[132]*w6 + r0[133]*w7 + r0[134]*w8;
    s += v; q += v * v;
  }
  #pragma unroll
  for (int off = 32; off > 0; off >>= 1){ s += __shfl_down(s, off); q += __shfl_down(q, off); }
  if ((tid & 63) == 0){ rs[tid >> 6] = s; rq[tid >> 6] = q; }
  __syncthreads();
  if (tid == 0){
    atomicAdd(&bnsum[c], rs[0] + rs[1] + rs[2] + rs[3]);
    atomicAdd(&bnsq[c],  rq[0] + rq[1] + rq[2] + rq[3]);
  }
}

// K1h: same, bf16 input (residual chain)
__global__ __launch_bounds__(256) void k_conv_stats_h(
    const unsigned short* __restrict__ x, const float* __restrict__ w,
    float* __restrict__ bnsum, float* __restrict__ bnsq){
  __shared__ float t[66 * 66];
  __shared__ float rs[4], rq[4];
  int bc = blockIdx.x; int c = bc & 255;
  const unsigned short* xp = x + (size_t)bc * 4096;
  int tid = threadIdx.x;
  for (int i = tid; i < 66 * 66; i += 256) t[i] = 0.f;
  __syncthreads();
  #pragma unroll
  for (int j = 0; j < 2; j++){
    int p8 = tid + j * 256;
    unsigned short vv[8];
    *reinterpret_cast<uint4*>(vv) = reinterpret_cast<const uint4*>(xp)[p8];
    int p = p8 * 8; int y = p >> 6, xx = p & 63;
    int base = (y + 1) * 66 + xx + 1;
    #pragma unroll
    for (int k = 0; k < 8; k++) t[base + k] = b2f(vv[k]);
  }
  __syncthreads();
  float w0 = w[c*9+0], w1 = w[c*9+1], w2 = w[c*9+2], w3 = w[c*9+3], w4 = w[c*9+4];
  float w5 = w[c*9+5], w6 = w[c*9+6], w7 = w[c*9+7], w8 = w[c*9+8];
  float s = 0.f, q = 0.f;
  #pragma unroll
  for (int j = 0; j < 16; j++){
    int p = tid + j * 256; int y = p >> 6, xx = p & 63;
    const float* r0 = &t[y * 66 + xx];
    float v = r0[0]*w0 + r0[1]*w1 + r0[2]*w2 + r0[66]*w3 + r0[67]*w4 + r0[68]*w5
            + r0[132]*w6 + r0[133]*w7 + r0[134]*w8;
    s += v; q += v * v;
  }
  #pragma unroll
  for (int off = 32; off > 0; off >>= 1){ s += __shfl_down(s, off); q += __shfl_down(q, off); }
  if ((tid & 63) == 0){ rs[tid >> 6] = s; rq[tid >> 6] = q; }
  __syncthreads();
  if (tid == 0){
    atomicAdd(&bnsum[c], rs[0] + rs[1] + rs[2] + rs[3]);
    atomicAdd(&bnsq[c],  rq[0] + rq[1] + rq[2] + rq[3]);
  }
}

// K2a: x1 = (1-a)*x + a*BN(conv(x)), fp32 in -> bf16 out
__global__ __launch_bounds__(256) void k_conv_bn_blend_f2h(
    const float* __restrict__ x, const float* __restrict__ w,
    const float* __restrict__ bnsum, const float* __restrict__ bnsq,
    const float* __restrict__ g, const float* __restrict__ bb,
    const float* __restrict__ alpha, unsigned short* __restrict__ out){
  __shared__ float t[66 * 66];
  int bc = blockIdx.x; int c = bc & 255;
  const float* xp = x + (size_t)bc * 4096;
  unsigned short* op = out + (size_t)bc * 4096;
  int tid = threadIdx.x;
  for (int i = tid; i < 66 * 66; i += 256) t[i] = 0.f;
  __syncthreads();
  #pragma unroll
  for (int j = 0; j < 4; j++){
    int p4 = tid + j * 256;
    float4 v = reinterpret_cast<const float4*>(xp)[p4];
    int p = p4 * 4; int y = p >> 6, xx = p & 63;
    int base = (y + 1) * 66 + xx + 1;
    t[base] = v.x; t[base + 1] = v.y; t[base + 2] = v.z; t[base + 3] = v.w;
  }
  __syncthreads();
  float w0 = w[c*9+0], w1 = w[c*9+1], w2 = w[c*9+2], w3 = w[c*9+3], w4 = w[c*9+4];
  float w5 = w[c*9+5], w6 = w[c*9+6], w7 = w[c*9+7], w8 = w[c*9+8];
  float m  = bnsum[c] * (1.f / 65536.f);
  float var = bnsq[c] * (1.f / 65536.f) - m * m;
  float sc = rsqrtf(var + 1e-5f) * g[c];
  float bias = bb[c];
  float a = sigm(alpha[c]);
  #pragma unroll
  for (int j = 0; j < 16; j++){
    int p = tid + j * 256; int y = p >> 6, xx = p & 63;
    const float* r0 = &t[y * 66 + xx];
    float v = r0[0]*w0 + r0[1]*w1 + r0[2]*w2 + r0[66]*w3 + r0[67]*w4 + r0[68]*w5
            + r0[132]*w6 + r0[133]*w7 + r0[134]*w8;
    float xv = t[(y + 1) * 66 + xx + 1];
    op[p] = f2b((1.f - a) * xv + a * ((v - m) * sc + bias));
  }
}

// K2b: x3 = (1-a)*x2 + a*BN2(conv(x2)), bf16 in -> bf16 out (in-place ok)
__global__ __launch_bounds__(256) void k_conv_bn_blend_h2h(
    const unsigned short* __restrict__ x, const float* __restrict__ w,
    const float* __restrict__ bnsum, const float* __restrict__ bnsq,
    const float* __restrict__ g, const float* __restrict__ bb,
    const float* __restrict__ alpha, unsigned short* __restrict__ out){
  __shared__ float t[66 * 66];
  int bc = blockIdx.x; int c = bc & 255;
  const unsigned short* xp = x + (size_t)bc * 4096;
  unsigned short* op = out + (size_t)bc * 4096;
  int tid = threadIdx.x;
  for (int i = tid; i < 66 * 66; i += 256) t[i] = 0.f;
  __syncthreads();
  #pragma unroll
  for (int j = 0; j < 2; j++){
    int p8 = tid + j * 256;
    unsigned short vv[8];
    *reinterpret_cast<uint4*>(vv) = reinterpret_cast<const uint4*>(xp)[p8];
    int p = p8 * 8; int y = p >> 6, xx = p & 63;
    int base = (y + 1) * 66 + xx + 1;
    #pragma unroll
    for (int k = 0; k < 8; k++) t[base + k] = b2f(vv[k]);
  }
  __syncthreads();
  float w0 = w[c*9+0], w1 = w[c*9+1], w2 = w[c*9+2], w3 = w[c*9+3], w4 = w[c*9+4];
  float w5 = w[c*9+5], w6 = w[c*9+6], w7 = w[c*9+7], w8 = w[c*9+8];
  float m  = bnsum[c] * (1.f / 65536.f);
  float var = bnsq[c] * (1.f / 65536.f) - m * m;
  float sc = rsqrtf(var + 1e-5f) * g[c];
  float bias = bb[c];
  float a = sigm(alpha[c]);
  #pragma unroll
  for (int j = 0; j < 16; j++){
    int p = tid + j * 256; int y = p >> 6, xx = p & 63;
    const float* r0 = &t[y * 66 + xx];
    float v = r0[0]*w0 + r0[1]*w1 + r0[2]*w2 + r0[66]*w3 + r0[67]*w4 + r0[68]*w5
            + r0[132]*w6 + r0[133]*w7 + r0[134]*w8;
    float xv = t[(y + 1) * 66 + xx + 1];
    op[p] = f2b((1.f - a) * xv + a * ((v - m) * sc + bias));
  }
}

// ---------------------------------------------------------------------------
// K2c: per-pixel LayerNorm over C (bf16 xres in) -> xf (b,c,l) + xfT (b,l,c)
__global__ __launch_bounds__(256) void k_ln(
    const unsigned short* __restrict__ x1, const float* __restrict__ lnw,
    const float* __restrict__ lnb, unsigned short* __restrict__ xf,
    unsigned short* __restrict__ xfT){
  __shared__ unsigned short st[256 * 65];            // [c][pixel], pad 65
  __shared__ float reds[4][64], redq[4][64];
  int b = blockIdx.x >> 6, lt = blockIdx.x & 63; int l0 = lt * 64;
  int t = threadIdx.x, w = t >> 6, lane = t & 63;
  const unsigned short* xp = x1 + ((size_t)b * 256) * 4096 + l0 + lane;
  float s = 0.f, q = 0.f;
  for (int i = 0; i < 64; i++){
    int c = w * 64 + i;
    unsigned short h = xp[(size_t)c * 4096];
    float v = b2f(h);
    s += v; q += v * v;
    st[c * 65 + lane] = h;
  }
  reds[w][lane] = s; redq[w][lane] = q;
  __syncthreads();
  s = reds[0][lane] + reds[1][lane] + reds[2][lane] + reds[3][lane];
  q = redq[0][lane] + redq[1][lane] + redq[2][lane] + redq[3][lane];
  float m = s * (1.f / 256.f);
  float r = rsqrtf(q * (1.f / 256.f) - m * m + 1e-5f);
  for (int i = 0; i < 64; i++){
    int c = w * 64 + i;
    float v = b2f(st[c * 65 + lane]);
    unsigned short h = f2b((v - m) * r * lnw[c] + lnb[c]);
    st[c * 65 + lane] = h;
    xf[((size_t)(b * 256 + c)) * 4096 + l0 + lane] = h;
  }
  __syncthreads();
  int p = t >> 4, cc = t & 15;                       // 16 lanes per pixel row
  for (int pi = 0; pi < 4; pi++){
    int px = p + pi * 16;
    #pragma unroll
    for (int j = 0; j < 2; j++){
      int c0 = (j * 16 + cc) * 8;
      unsigned short vv[8];
      #pragma unroll
      for (int k = 0; k < 8; k++) vv[k] = st[(c0 + k) * 65 + px];
      *reinterpret_cast<uint4*>(&xfT[((size_t)(b * 4096 + l0 + px)) * 256 + c0]) =
          *reinterpret_cast<uint4*>(vv);
    }
  }
}

// K2d: x3 bf16 (b,c,l) -> x3T bf16 (b,l,c), COLUMN-SWIZZLED for ffn1:
// x3T[p][c ^ ((p&7)<<3)] = x3[c][p]  (within 64-col blocks; granule-safe)
__global__ __launch_bounds__(256) void k_xt(
    const unsigned short* __restrict__ x, unsigned short* __restrict__ xT){
  __shared__ unsigned short st[256 * 65];
  int b = blockIdx.x >> 6, lt = blockIdx.x & 63; int l0 = lt * 64;
  int t = threadIdx.x, w = t >> 6, lane = t & 63;
  const unsigned short* xp = x + ((size_t)b * 256) * 4096 + l0 + lane;
  for (int i = 0; i < 64; i++){
    int c = w * 64 + i;
    st[c * 65 + lane] = xp[(size_t)c * 4096];
  }
  __syncthreads();
  int p = t >> 4, cc = t & 15;
  for (int pi = 0; pi < 4; pi++){
    int px = p + pi * 16;
    int key = (px & 7) << 3;                         // l0 is a multiple of 8
    #pragma unroll
    for (int j = 0; j < 2; j++){
      int c0 = (j * 16 + cc) * 8;
      unsigned short vv[8];
      #pragma unroll
      for (int k = 0; k < 8; k++) vv[k] = st[(c0 + k) * 65 + px];
      *reinterpret_cast<uint4*>(&xT[((size_t)(b * 4096 + l0 + px)) * 256 + (c0 ^ key)]) =
          *reinterpret_cast<uint4*>(vv);
    }
  }
}

// ---------------------------------------------------------------------------
// K3: BCdt = bcdt_w(192x256) @ xf + bias  (MFMA, operands direct from global)
__global__ __launch_bounds__(256) void k_bcdt(
    const unsigned short* __restrict__ xfT, const unsigned short* __restrict__ wb,
    const float* __restrict__ bias, unsigned short* __restrict__ outp){
  int blk = blockIdx.x; int b = blk >> 6, lt = blk & 63; int l0 = lt * 64;
  int t = threadIdx.x; int wv = t >> 6, lane = t & 63;
  int col = lane & 15, g = lane >> 4;
  f32x4 acc[3][4];
  #pragma unroll
  for (int mm = 0; mm < 3; mm++)
    #pragma unroll
    for (int nn = 0; nn < 4; nn++) acc[mm][nn] = zero4();
  for (int k = 0; k < 8; k++){
    bf16x8 av[3], bv[4];
    #pragma unroll
    for (int mm = 0; mm < 3; mm++){
      int o = (wv * 3 + mm) * 16 + col;
      av[mm] = ldb8g(&wb[(size_t)o * 256 + k * 32 + g * 8]);
    }
    #pragma unroll
    for (int nn = 0; nn < 4; nn++){
      int l = l0 + nn * 16 + col;
      bv[nn] = ldb8g(&xfT[((size_t)(b * 4096 + l)) * 256 + k * 32 + g * 8]);
    }
    #pragma unroll
    for (int mm = 0; mm < 3; mm++)
      #pragma unroll
      for (int nn = 0; nn < 4; nn++) acc[mm][nn] = mfma16(av[mm], bv[nn], acc[mm][nn]);
  }
  #pragma unroll
  for (int mm = 0; mm < 3; mm++)
    #pragma unroll
    for (int nn = 0; nn < 4; nn++)
      #pragma unroll
      for (int r = 0; r < 4; r++){
        int o = (wv * 3 + mm) * 16 + g * 4 + r;
        int l = l0 + nn * 16 + col;
        outp[((size_t)(b * 192 + o)) * 4096 + l] = f2b(acc[mm][nn][r] + bias[o]);
      }
}

// ---------------------------------------------------------------------------
// K4: depthwise conv on BCdt (192 ch) + bias; dt channels also reduce softmax
// stats (max & sumexp over the full 4096-pixel plane == softmax row).
__global__ __launch_bounds__(256) void k_conv_mid(
    const unsigned short* __restrict__ in, const float* __restrict__ w,
    const float* __restrict__ wbias, unsigned short* __restrict__ outp,
    float* __restrict__ smmax, float* __restrict__ smsum){
  __shared__ float t[66 * 66];
  __shared__ float red[8];
  int blk = blockIdx.x; int b = blk / 192, ch = blk % 192;
  const unsigned short* xp = in + (size_t)blk * 4096;
  unsigned short* op = outp + (size_t)blk * 4096;
  int tid = threadIdx.x;
  for (int i = tid; i < 66 * 66; i += 256) t[i] = 0.f;
  __syncthreads();
  #pragma unroll
  for (int j = 0; j < 2; j++){
    int p8 = tid + j * 256;
    unsigned short vv[8];
    *reinterpret_cast<uint4*>(vv) = reinterpret_cast<const uint4*>(xp)[p8];
    int p = p8 * 8; int y = p >> 6, xx = p & 63;
    int base = (y + 1) * 66 + xx + 1;
    #pragma unroll
    for (int k = 0; k < 8; k++) t[base + k] = b2f(vv[k]);
  }
  __syncthreads();
  float w0 = w[ch*9+0], w1 = w[ch*9+1], w2 = w[ch*9+2], w3 = w[ch*9+3], w4 = w[ch*9+4];
  float w5 = w[ch*9+5], w6 = w[ch*9+6], w7 = w[ch*9+7], w8 = w[ch*9+8];
  float bv = wbias[ch];
  float vloc[16];
  float mx = -1e30f;
  #pragma unroll
  for (int j = 0; j < 16; j++){
    int p = tid + j * 256; int y = p >> 6, xx = p & 63;
    const float* r0 = &t[y * 66 + xx];
    float v = r0[0]*w0 + r0[1]*w1 + r0[2]*w2 + r0[66]*w3 + r0[67]*w4 + r0[68]*w5
            + r0[132]*w6 + r0[133]*w7 + r0[134]*w8 + bv;
    unsigned short h = f2b(v);
    op[p] = h;
    float vb = b2f(h);
    vloc[j] = vb;
    mx = fmaxf(mx, vb);
  }
  if (ch >= 128){                                    // dt channel: softmax stats
    #pragma unroll
    for (int off = 32; off > 0; off >>= 1) mx = fmaxf(mx, __shfl_down(mx, off));
    if ((tid & 63) == 0) red[tid >> 6] = mx;
    __syncthreads();
    float M = fmaxf(fmaxf(red[0], red[1]), fmaxf(red[2], red[3]));
    float se = 0.f;
    #pragma unroll
    for (int j = 0; j < 16; j++) se += __expf(vloc[j] - M);
    #pragma unroll
    for (int off = 32; off > 0; off >>= 1) se += __shfl_down(se, off);
    if ((tid & 63) == 0) red[4 + (tid >> 6)] = se;
    __syncthreads();
    if (tid == 0){
      smmax[b * 64 + ch - 128] = M;
      smsum[b * 64 + ch - 128] = red[4] + red[5] + red[6] + red[7];
    }
  }
}

// K5 (merged): blocks 0..1023: AB = softmax(dt)*Bm; blocks 1024..2047: CmT.
__global__ __launch_bounds__(256) void k_ab_cmt(
    const unsigned short* __restrict__ bc, const float* __restrict__ smmax,
    const float* __restrict__ smsum, unsigned short* __restrict__ ab,
    unsigned short* __restrict__ cmt){
  __shared__ float t[64 * 65];
  int blk = blockIdx.x;
  if (blk < 1024){
    int b = blk >> 6, s = blk & 63;
    const unsigned short* dt = bc + ((size_t)(b * 192 + 128 + s)) * 4096;
    const unsigned short* bm = bc + ((size_t)(b * 192 + s)) * 4096;
    unsigned short* o = ab + ((size_t)(b * 64 + s)) * 4096;
    float M = smmax[b * 64 + s];
    float inv = 1.f / smsum[b * 64 + s];
    for (int i = threadIdx.x; i < 4096; i += 256)
      o[i] = f2b(__expf(b2f(dt[i]) - M) * inv * b2f(bm[i]));
    return;
  }
  blk -= 1024;
  int b = blk >> 6, lt = blk & 63; int l0 = lt * 64;
  int tid = threadIdx.x;
  #pragma unroll
  for (int it = 0; it < 2; it++){
    int row = (tid >> 3) + it * 32;                  // s
    int lq = (tid & 7) * 8;
    const unsigned short* p = bc + ((size_t)(b * 192 + 64 + row)) * 4096 + l0 + lq;
    unsigned short vv[8];
    *reinterpret_cast<uint4*>(vv) = *reinterpret_cast<const uint4*>(p);
    #pragma unroll
    for (int k = 0; k < 8; k++) t[row * 65 + lq + k] = b2f(vv[k]);
  }
  __syncthreads();
  #pragma unroll
  for (int it = 0; it < 2; it++){
    int l = (tid >> 3) + it * 32;
    int sq = (tid & 7) * 8;
    unsigned short vv[8];
    #pragma unroll
    for (int k = 0; k < 8; k++) vv[k] = f2b(t[(sq + k) * 65 + l]);
    *reinterpret_cast<uint4*>(&cmt[((size_t)(b * 4096 + l0 + l)) * 64 + sq]) =
        *reinterpret_cast<uint4*>(vv);
  }
}

// ---------------------------------------------------------------------------
// K6: hT[b,s,c] += sum_l AB[s,l]*xf[c,l]  -- 16 K-chunks over l, grid 256
__global__ __launch_bounds__(512) void k_h(
    const unsigned short* __restrict__ ab, const unsigned short* __restrict__ xf,
    float* __restrict__ hpart){
  int blk = blockIdx.x; int b = blk & 15, chunk = blk >> 4;   // grid 256
  int t = threadIdx.x; int wv = t >> 6, lane = t & 63;
  int col = lane & 15, g = lane >> 4;
  int mt = wv & 3, nh = wv >> 2;
  f32x4 acc[8];
  #pragma unroll
  for (int nn = 0; nn < 8; nn++) acc[nn] = zero4();
  int lbase = chunk * 256;
  const unsigned short* ap = ab + ((size_t)(b * 64 + mt * 16 + col)) * 4096 + lbase + g * 8;
  for (int ks = 0; ks < 8; ks++){
    bf16x8 av = ldb8g(ap + ks * 32);
    #pragma unroll
    for (int nn = 0; nn < 8; nn++){
      int c = nh * 128 + nn * 16 + col;
      bf16x8 bv = ldb8g(&xf[((size_t)(b * 256 + c)) * 4096 + lbase + ks * 32 + g * 8]);
      acc[nn] = mfma16(av, bv, acc[nn]);
    }
  }
  #pragma unroll
  for (int nn = 0; nn < 8; nn++)
    #pragma unroll
    for (int r = 0; r < 4; r++){
      int s = mt * 16 + g * 4 + r;
      int c = nh * 128 + nn * 16 + col;
      hpart[(((size_t)chunk * 16 + b) * 64 + s) * 256 + c] = acc[nn][r];
    }
}

// K7pre: sum 16 k-partials -> bf16 [b][s][c]
__global__ __launch_bounds__(256) void k_hsum(
    const float* __restrict__ hp, unsigned short* __restrict__ hsb){
  int i = blockIdx.x * 256 + threadIdx.x;            // 262144
  float s = 0.f;
  #pragma unroll
  for (int c = 0; c < 16; c++) s += hp[(size_t)c * 262144 + i];
  hsb[i] = f2b(s);
}

// K7a (MFMA): u = hzw @ h + hzb; hh1 = u * (silu(z) + D)  -> bf16 [b][s][o]
__global__ __launch_bounds__(256) void k_hz(
    const unsigned short* __restrict__ hsb, const unsigned short* __restrict__ hzwb,
    const float* __restrict__ hzb, const float* __restrict__ Dp,
    unsigned short* __restrict__ hh1b){
  int blk = blockIdx.x; int b = blk >> 2, og = blk & 3;
  int t = threadIdx.x, wv = t >> 6, lane = t & 63;
  int col = lane & 15, g = lane >> 4;
  int ou = og * 64 + wv * 16;                        // u-row base (0..255)
  int oz = 256 + ou;                                 // paired z-row
  f32x4 au[4], az[4];
  #pragma unroll
  for (int nn = 0; nn < 4; nn++){ au[nn] = zero4(); az[nn] = zero4(); }
  const unsigned short* bbase = hsb + (size_t)b * 64 * 256;
  for (int k = 0; k < 8; k++){
    bf16x8 a_u = ldb8g(&hzwb[(size_t)(ou + col) * 256 + k * 32 + g * 8]);
    bf16x8 a_z = ldb8g(&hzwb[(size_t)(oz + col) * 256 + k * 32 + g * 8]);
    bf16x8 bv[4];
    #pragma unroll
    for (int nn = 0; nn < 4; nn++)
      bv[nn] = ldb8g(bbase + (size_t)(nn * 16 + col) * 256 + k * 32 + g * 8);
    #pragma unroll
    for (int nn = 0; nn < 4; nn++){
      au[nn] = mfma16(a_u, bv[nn], au[nn]);
      az[nn] = mfma16(a_z, bv[nn], az[nn]);
    }
  }
  float Dv = Dp[0];
  #pragma unroll
  for (int nn = 0; nn < 4; nn++){
    int s = nn * 16 + col;
    float hv[4];
    #pragma unroll
    for (int r = 0; r < 4; r++){
      int o = ou + g * 4 + r;
      float u = au[nn][r] + hzb[o];
      float z = az[nn][r] + hzb[o + 256];
      float sl = z / (1.f + __expf(-z));
      hv[r] = u * (sl + Dv);
    }
    unsigned int p0 = cvtpk(hv[0], hv[1]), p1 = cvtpk(hv[2], hv[3]);
    uint2 pv; pv.x = p0; pv.y = p1;
    *reinterpret_cast<uint2*>(&hh1b[((size_t)(b * 64 + s)) * 256 + ou + g * 4]) = pv;
  }
}

// K7b (MFMA): hh2[b][d][s] = outw @ hh1 + out_b  (bf16)
__global__ __launch_bounds__(256) void k_out(
    const unsigned short* __restrict__ hh1b, const unsigned short* __restrict__ outwb,
    const float* __restrict__ ob, unsigned short* __restrict__ hh2){
  int blk = blockIdx.x; int b = blk >> 2, dg = blk & 3;
  int t = threadIdx.x, wv = t >> 6, lane = t & 63;
  int col = lane & 15, g = lane >> 4;
  int d0 = dg * 64 + wv * 16;
  f32x4 acc[4];
  #pragma unroll
  for (int nn = 0; nn < 4; nn++) acc[nn] = zero4();
  const unsigned short* bbase = hh1b + (size_t)b * 64 * 256;
  for (int k = 0; k < 8; k++){
    bf16x8 a = ldb8g(&outwb[(size_t)(d0 + col) * 256 + k * 32 + g * 8]);
    bf16x8 bv[4];
    #pragma unroll
    for (int nn = 0; nn < 4; nn++)
      bv[nn] = ldb8g(bbase + (size_t)(nn * 16 + col) * 256 + k * 32 + g * 8);
    #pragma unroll
    for (int nn = 0; nn < 4; nn++) acc[nn] = mfma16(a, bv[nn], acc[nn]);
  }
  #pragma unroll
  for (int nn = 0; nn < 4; nn++){
    int s = nn * 16 + col;
    #pragma unroll
    for (int r = 0; r < 4; r++){
      int d = d0 + g * 4 + r;
      hh2[((size_t)(b * 256 + d)) * 64 + s] = f2b(acc[nn][r] + ob[d]);
    }
  }
}

// K8: y = hh2 @ Cm ; x2 = (1-a1)*x1 + a1*y  (in-place on bf16 xres)
__global__ __launch_bounds__(256) void k_y_blend(
    const unsigned short* __restrict__ hh2, const unsigned short* __restrict__ cmt,
    const float* __restrict__ alpha, unsigned short* __restrict__ x){
  int blk = blockIdx.x; int b = blk >> 6, lt = blk & 63; int l0 = lt * 64;
  int t = threadIdx.x; int wv = t >> 6, lane = t & 63;
  int col = lane & 15, g = lane >> 4;
  f32x4 acc[4][4];
  #pragma unroll
  for (int mm = 0; mm < 4; mm++)
    #pragma unroll
    for (int nn = 0; nn < 4; nn++) acc[mm][nn] = zero4();
  #pragma unroll
  for (int k = 0; k < 2; k++){
    bf16x8 av[4], bv[4];
    #pragma unroll
    for (int mm = 0; mm < 4; mm++){
      int c = (wv * 4 + mm) * 16 + col;
      av[mm] = ldb8g(&hh2[((size_t)(b * 256 + c)) * 64 + k * 32 + g * 8]);
    }
    #pragma unroll
    for (int nn = 0; nn < 4; nn++){
      int l = l0 + nn * 16 + col;
      bv[nn] = ldb8g(&cmt[((size_t)(b * 4096 + l)) * 64 + k * 32 + g * 8]);
    }
    #pragma unroll
    for (int mm = 0; mm < 4; mm++)
      #pragma unroll
      for (int nn = 0; nn < 4; nn++) acc[mm][nn] = mfma16(av[mm], bv[nn], acc[mm][nn]);
  }
  #pragma unroll
  for (int mm = 0; mm < 4; mm++)
    #pragma unroll
    for (int r = 0; r < 4; r++){
      int c = (wv * 4 + mm) * 16 + g * 4 + r;
      float a1 = sigm(alpha[c]);
      #pragma unroll
      for (int nn = 0; nn < 4; nn++){
        int l = l0 + nn * 16 + col;
        size_t idx = ((size_t)(b * 256 + c)) * 4096 + l;
        float xv = b2f(x[idx]);
        x[idx] = f2b((1.f - a1) * xv + a1 * acc[mm][nn][r]);
      }
    }
}

// ---------------------------------------------------------------------------
// K11a: H[l][o] = gelu(W1 @ x3 + b1) for one batch-half (m97 structure).
// A (w1b) and B (x3T) are pre-swizzled in global; fragment reads apply the
// matching XOR (koff ^ ((col&7)<<3)). H written column-swizzled for ffn2.
__global__ __launch_bounds__(256, 4) void k_ffn1(
    const unsigned short* __restrict__ xT, const unsigned short* __restrict__ w1b,
    const float* __restrict__ b1, unsigned short* __restrict__ Hh, int b0){
  __shared__ unsigned short smem[17408];             // max(A+B 32KB, bounce 34KB)
  unsigned short* At = smem;                         // [128][64]
  unsigned short* Bt = smem + 8192;                  // [128][64]
  int wk = ((blockIdx.x & 7) << 8) + (blockIdx.x >> 3);   // bijective XCD swizzle
  int mt = wk & 7, nt = wk >> 3;
  int t = threadIdx.x, wv = t >> 6, lane = t & 63;
  int col = lane & 15, g = lane >> 4;
  int wr = wv >> 1, wc = wv & 1;
  int fkey = (col & 7) << 3;                         // fragment-read XOR key
  const unsigned short* ag = w1b + (size_t)(mt * 128) * 256;
  const unsigned short* bg = xT + ((size_t)b0 * 4096 + (size_t)nt * 128) * 256;
  float bias[4][4];
  #pragma unroll
  for (int mm = 0; mm < 4; mm++)
    #pragma unroll
    for (int r = 0; r < 4; r++)
      bias[mm][r] = b1[mt * 128 + wr * 64 + mm * 16 + g * 4 + r];
  f32x4 acc[4][4];
  #pragma unroll
  for (int mm = 0; mm < 4; mm++)
    #pragma unroll
    for (int nn = 0; nn < 4; nn++) acc[mm][nn] = zero4();
  for (int kk = 0; kk < 4; kk++){
    __syncthreads();
    #pragma unroll
    for (int j = 0; j < 4; j++){
      int id = t + j * 256;                          // 0..1023
      int row = id >> 3, kc = (id & 7) * 8;
      gload_lds16(ag + (size_t)row * 256 + kk * 64 + kc, At + id * 8);
      gload_lds16(bg + (size_t)row * 256 + kk * 64 + kc, Bt + id * 8);
    }
    __syncthreads();
    #pragma unroll
    for (int ks = 0; ks < 2; ks++){
      int koff = (ks * 32 + g * 8) ^ fkey;
      bf16x8 av[4], bv[4];
      #pragma unroll
      for (int mm = 0; mm < 4; mm++)
        av[mm] = *reinterpret_cast<const bf16x8*>(&At[(wr * 64 + mm * 16 + col) * 64 + koff]);
      #pragma unroll
      for (int nn = 0; nn < 4; nn++)
        bv[nn] = *reinterpret_cast<const bf16x8*>(&Bt[(wc * 64 + nn * 16 + col) * 64 + koff]);
      #pragma unroll
      for (int mm = 0; mm < 4; mm++)
        #pragma unroll
        for (int nn = 0; nn < 4; nn++)
          acc[mm][nn] = mfma16(av[mm], bv[nn], acc[mm][nn]);
    }
  }
  __syncthreads();
  // cheap gelu -> cvt_pk -> bounce [128 l][136 o-pad]
  #pragma unroll
  for (int mm = 0; mm < 4; mm++){
    int o4 = wr * 64 + mm * 16 + g * 4;
    #pragma unroll
    for (int nn = 0; nn < 4; nn++){
      int lloc = wc * 64 + nn * 16 + col;
      float gv[4];
      #pragma unroll
      for (int r = 0; r < 4; r++)
        gv[r] = gelu_fast(acc[mm][nn][r] + bias[mm][r]);
      uint2 pv; pv.x = cvtpk(gv[0], gv[1]); pv.y = cvtpk(gv[2], gv[3]);
      *reinterpret_cast<uint2*>(&smem[lloc * 136 + o4]) = pv;
    }
  }
  __syncthreads();
  size_t hb = (size_t)nt * 128;
  #pragma unroll
  for (int j = 0; j < 8; j++){
    int id = t + j * 256;                            // 0..2047
    int l = id >> 4, oc = id & 15;
    uint4 v = *reinterpret_cast<const uint4*>(&smem[l * 136 + oc * 8]);
    int cg = (oc * 8) ^ ((l & 7) << 3);              // H column-swizzle (granule)
    *reinterpret_cast<uint4*>(&Hh[(hb + l) * 1024 + mt * 128 + cg]) = v;
  }
}

// K11b: out_fp32 = (1-a3)*x3(bf16) + a3*(W2 @ H + b2) for one batch-half.
// A (w2b) and B (H) pre-swizzled; fragment reads apply matching XOR.
__global__ __launch_bounds__(256, 4) void k_ffn2(
    const unsigned short* __restrict__ Hh, const unsigned short* __restrict__ w2b,
    const float* __restrict__ b2, const float* __restrict__ alpha3,
    const unsigned short* __restrict__ xres, float* __restrict__ outp, int b0){
  __shared__ unsigned short At[128 * 64];            // 16KB
  __shared__ unsigned short Bt[64 * 64];             // 8KB
  int wk = ((blockIdx.x & 7) << 7) + (blockIdx.x >> 3);   // bijective XCD swizzle
  int mt = wk & 1, nt = wk >> 1;                     // nt 0..511 (64-px tiles)
  int t = threadIdx.x, wv = t >> 6, lane = t & 63;
  int col = lane & 15, g = lane >> 4;
  int wr = wv >> 1, wc = wv & 1;                     // wave: 64d x 32l
  int fkey = (col & 7) << 3;
  const unsigned short* ag = w2b + (size_t)(mt * 128) * 1024;
  const unsigned short* bg = Hh + (size_t)(nt * 64) * 1024;
  f32x4 acc[4][2];
  #pragma unroll
  for (int mm = 0; mm < 4; mm++)
    #pragma unroll
    for (int nn = 0; nn < 2; nn++) acc[mm][nn] = zero4();
  for (int kk = 0; kk < 16; kk++){
    __syncthreads();
    #pragma unroll
    for (int j = 0; j < 4; j++){                     // A: 1024 x 16B
      int id = t + j * 256;
      int row = id >> 3, kc = (id & 7) * 8;
      gload_lds16(ag + (size_t)row * 1024 + kk * 64 + kc, At + id * 8);
    }
    #pragma unroll
    for (int j = 0; j < 2; j++){                     // B: 512 x 16B
      int id = t + j * 256;
      int row = id >> 3, kc = (id & 7) * 8;
      gload_lds16(bg + (size_t)row * 1024 + kk * 64 + kc, Bt + id * 8);
    }
    __syncthreads();
    #pragma unroll
    for (int ks = 0; ks < 2; ks++){
      int koff = (ks * 32 + g * 8) ^ fkey;
      bf16x8 av[4], bv[2];
      #pragma unroll
      for (int mm = 0; mm < 4; mm++)
        av[mm] = *reinterpret_cast<const bf16x8*>(&At[(wr * 64 + mm * 16 + col) * 64 + koff]);
      #pragma unroll
      for (int nn = 0; nn < 2; nn++)
        bv[nn] = *reinterpret_cast<const bf16x8*>(&Bt[(wc * 32 + nn * 16 + col) * 64 + koff]);
      #pragma unroll
      for (int mm = 0; mm < 4; mm++)
        #pragma unroll
        for (int nn = 0; nn < 2; nn++)
          acc[mm][nn] = mfma16(av[mm], bv[nn], acc[mm][nn]);
    }
  }
  #pragma unroll
  for (int mm = 0; mm < 4; mm++)
    #pragma unroll
    for (int r = 0; r < 4; r++){
      int d = mt * 128 + wr * 64 + mm * 16 + g * 4 + r;
      float a3 = sigm(alpha3[d]);
      float bias = b2[d];
      #pragma unroll
      for (int nn = 0; nn < 2; nn++){
        int lh = nt * 64 + wc * 32 + nn * 16 + col;
        int b = b0 + (lh >> 12);
        int l = lh & 4095;
        size_t idx = ((size_t)(b * 256 + d)) * 4096 + l;
        float xv = b2f(xres[idx]);
        outp[idx] = (1.f - a3) * xv + a3 * (acc[mm][nn][r] + bias);
      }
    }
}

// ---------------------------------------------------------------------------
extern "C" void kernel_launch(void* const* d_in, const int* in_sizes, int n_in,
                              void* d_out, int out_size, void* d_ws, size_t ws_size,
                              hipStream_t stream){
  (void)in_sizes; (void)n_in; (void)out_size; (void)ws_size;
  const float* x      = (const float*)d_in[0];
  const float* alpha  = (const float*)d_in[1];
  const float* dw1_w  = (const float*)d_in[2];
  const float* bn1_g  = (const float*)d_in[3];
  const float* bn1_b  = (const float*)d_in[4];
  const float* dw2_w  = (const float*)d_in[5];
  const float* bn2_g  = (const float*)d_in[6];
  const float* bn2_b  = (const float*)d_in[7];
  const float* ln_w   = (const float*)d_in[8];
  const float* ln_b   = (const float*)d_in[9];
  const float* bcdt_w = (const float*)d_in[10];
  const float* bcdt_b = (const float*)d_in[11];
  const float* mdw_w  = (const float*)d_in[12];
  const float* mdw_b  = (const float*)d_in[13];
  const float* hz_w   = (const float*)d_in[14];
  const float* hz_b   = (const float*)d_in[15];
  const float* out_w  = (const float*)d_in[16];
  const float* out_b  = (const float*)d_in[17];
  // d_in[18] = A: cancels exactly in softmax over L (constant shift per row)
  const float* Dvec   = (const float*)d_in[19];
  const float* ffn_w1 = (const float*)d_in[20];
  const float* ffn_b1 = (const float*)d_in[21];
  const float* ffn_w2 = (const float*)d_in[22];
  const float* ffn_b2 = (const float*)d_in[23];
  float* out = (float*)d_out;
  char* ws = (char*)d_ws;

  // ---- ws map (bf16 residual chain; lifetimes audited, R15 layout) ----
  const size_t OFF_XRES  = 0;
  const size_t OFF_XF    = 33554432;
  const size_t OFF_XFT   = 67108864;
  const size_t OFF_BCC   = 67108864;
  const size_t OFF_BCRAW = 100663296;
  const size_t OFF_AB    = 100663296;
  const size_t OFF_CMT   = 109051904;
  const size_t OFF_HPART = 117440512;
  const size_t OFF_X3T   = 33554432;
  const size_t OFF_H     = 67108864;
  const size_t OFF_W1B   = 134217728;
  const size_t OFF_W2B   = 134742016;
  const size_t OFF_BWB   = 135266304;
  const size_t OFF_HZWB  = 135364608;
  const size_t OFF_OUTWB = 135626752;
  const size_t OFF_HSB   = 135757824;
  const size_t OFF_HH1B  = 136282112;
  const size_t OFF_HH2   = 136806400;
  const size_t OFF_STATS = 137330688;
  const size_t OFF_SMMAX = 137334784;
  const size_t OFF_SMSUM = 137338880;

  unsigned short* xres  = (unsigned short*)(ws + OFF_XRES);
  unsigned short* xf    = (unsigned short*)(ws + OFF_XF);
  unsigned short* xfT   = (unsigned short*)(ws + OFF_XFT);
  unsigned short* bcc   = (unsigned short*)(ws + OFF_BCC);
  unsigned short* bcraw = (unsigned short*)(ws + OFF_BCRAW);
  unsigned short* ab    = (unsigned short*)(ws + OFF_AB);
  unsigned short* cmt   = (unsigned short*)(ws + OFF_CMT);
  float* hpart = (float*)(ws + OFF_HPART);
  unsigned short* x3T  = (unsigned short*)(ws + OFF_X3T);
  unsigned short* Hbuf = (unsigned short*)(ws + OFF_H);
  unsigned short* w1b = (unsigned short*)(ws + OFF_W1B);
  unsigned short* w2b = (unsigned short*)(ws + OFF_W2B);
  unsigned short* bwb = (unsigned short*)(ws + OFF_BWB);
  unsigned short* hzwb  = (unsigned short*)(ws + OFF_HZWB);
  unsigned short* outwb = (unsigned short*)(ws + OFF_OUTWB);
  unsigned short* hsb  = (unsigned short*)(ws + OFF_HSB);
  unsigned short* hh1b = (unsigned short*)(ws + OFF_HH1B);
  unsigned short* hh2  = (unsigned short*)(ws + OFF_HH2);
  float* bn1sum = (float*)(ws + OFF_STATS);
  float* bn1sq  = bn1sum + 256;
  float* bn2sum = bn1sum + 512;
  float* bn2sq  = bn1sum + 768;
  float* smmax = (float*)(ws + OFF_SMMAX);
  float* smsum = (float*)(ws + OFF_SMSUM);

  hipMemsetAsync(ws + OFF_STATS, 0, 4096, stream);
  k_setup<<<1024, 256, 0, stream>>>(ffn_w1, ffn_w2, bcdt_w, hz_w, out_w,
                                    w1b, w2b, bwb, hzwb, outwb);
  // stage 1: x1 = blend(x, BN(conv(x))), into xres (bf16)
  k_conv_stats<<<4096, 256, 0, stream>>>(x, dw1_w, bn1sum, bn1sq);
  k_conv_bn_blend_f2h<<<4096, 256, 0, stream>>>(x, dw1_w, bn1sum, bn1sq,
                                                bn1_g, bn1_b, alpha + 0, xres);
  // LN -> xf/xfT bf16
  k_ln<<<1024, 256, 0, stream>>>(xres, ln_w, ln_b, xf, xfT);
  // mixer
  k_bcdt<<<1024, 256, 0, stream>>>(xfT, bwb, bcdt_b, bcraw);
  k_conv_mid<<<3072, 256, 0, stream>>>(bcraw, mdw_w, mdw_b, bcc, smmax, smsum);
  k_ab_cmt<<<2048, 256, 0, stream>>>(bcc, smmax, smsum, ab, cmt);
  k_h<<<256, 512, 0, stream>>>(ab, xf, hpart);
  k_hsum<<<1024, 256, 0, stream>>>(hpart, hsb);
  k_hz<<<64, 256, 0, stream>>>(hsb, hzwb, hz_b, Dvec, hh1b);
  k_out<<<64, 256, 0, stream>>>(hh1b, outwb, out_b, hh2);
  k_y_blend<<<1024, 256, 0, stream>>>(hh2, cmt, alpha + 256, xres);
  // stage 2: x3 = blend(x2, BN2(conv2(x2))), in-place on xres (bf16)
  k_conv_stats_h<<<4096, 256, 0, stream>>>(xres, dw2_w, bn2sum, bn2sq);
  k_conv_bn_blend_h2h<<<4096, 256, 0, stream>>>(xres, dw2_w, bn2sum, bn2sq,
                                                bn2_g, bn2_b, alpha + 512, xres);
  // x3 -> x3T bf16 (column-swizzled for ffn1)
  k_xt<<<1024, 256, 0, stream>>>(xres, x3T);
  // FFN in two batch-halves; ffn2 writes d_out fp32 (blend with bf16 x3)
  k_ffn1<<<2048, 256, 0, stream>>>(x3T, w1b, ffn_b1, Hbuf, 0);
  k_ffn2<<<1024, 256, 0, stream>>>(Hbuf, w2b, ffn_b2, alpha + 768, xres, out, 0);
  k_ffn1<<<2048, 256, 0, stream>>>(x3T, w1b, ffn_b1, Hbuf, 8);
  k_ffn2<<<1024, 256, 0, stream>>>(Hbuf, w2b, ffn_b2, alpha + 768, xres, out, 8);
}

// Round 17
// 358.700 us; speedup vs baseline: 1.0250x; 1.0250x over previous
//
#include <hip/hip_runtime.h>
#include <stdint.h>

// ---------------------------------------------------------------------------
// EfficientVIM block, MI355X. Dims: B=16, C=256, H=W=64, L=4096, S=64,
// CONV_DIM=192, HID=1024. All GEMMs via mfma_f32_16x16x32_bf16 (fp32 accum).
// R17: exact revert to R15 (best, 359.0us). R16's T2 swizzle regressed +8.7us
// (regime-table confirmed: 2-phase loops hide ds_read conflicts under the
// stage/barrier drain; swizzle's XOR+scatter costs were net-negative).
// ---------------------------------------------------------------------------

typedef __attribute__((ext_vector_type(8))) short bf16x8;
typedef __attribute__((ext_vector_type(4))) float f32x4;

__device__ __forceinline__ unsigned short f2b(float f){
  union { float f; unsigned int u; } v; v.f = f;
  unsigned int r = v.u + 0x7FFFu + ((v.u >> 16) & 1u);   // RNE
  return (unsigned short)(r >> 16);
}
__device__ __forceinline__ float b2f(unsigned short h){
  union { unsigned int u; float f; } v; v.u = ((unsigned int)h) << 16;
  return v.f;
}
__device__ __forceinline__ float sigm(float x){ return 1.0f / (1.0f + __expf(-x)); }
// tanh-approx gelu in sigmoid form: v * sigmoid(2u), 2u*log2e folded in.
__device__ __forceinline__ float gelu_fast(float v){
  float t = v * (-2.3022059f - 0.10294886f * v * v);
  float e = __builtin_amdgcn_exp2f(t);
  return v * __builtin_amdgcn_rcpf(1.0f + e);
}
__device__ __forceinline__ unsigned int cvtpk(float lo, float hi){
  unsigned int r;
  asm volatile("v_cvt_pk_bf16_f32 %0, %1, %2" : "=v"(r) : "v"(lo), "v"(hi));
  return r;
}
__device__ __forceinline__ f32x4 mfma16(bf16x8 a, bf16x8 b, f32x4 c){
  return __builtin_amdgcn_mfma_f32_16x16x32_bf16(a, b, c, 0, 0, 0);
}
__device__ __forceinline__ bf16x8 ldb8g(const unsigned short* p){
  return *reinterpret_cast<const bf16x8*>(p);
}
__device__ __forceinline__ f32x4 zero4(){ f32x4 v = {0.f, 0.f, 0.f, 0.f}; return v; }
__device__ __forceinline__ void gload_lds16(const unsigned short* g, unsigned short* l){
  __builtin_amdgcn_global_load_lds(
      (const __attribute__((address_space(1))) void*)g,
      (__attribute__((address_space(3))) void*)l, 16, 0, 0);
}

// ---------------------------------------------------------------------------
// K0: weight conversion (all bf16, natural [row][k] layouts)
__global__ __launch_bounds__(256) void k_setup(
    const float* __restrict__ w1, const float* __restrict__ w2,
    const float* __restrict__ bw, const float* __restrict__ hzw,
    const float* __restrict__ outw,
    unsigned short* __restrict__ w1b, unsigned short* __restrict__ w2b,
    unsigned short* __restrict__ bwb, unsigned short* __restrict__ hzwb,
    unsigned short* __restrict__ outwb){
  int tid = blockIdx.x * 256 + threadIdx.x;          // grid 1024 -> 262144
  if (tid < 1024 * 256){ w1b[tid] = f2b(w1[tid]); w2b[tid] = f2b(w2[tid]); }
  if (tid < 192 * 256)  bwb[tid] = f2b(bw[tid]);
  if (tid < 512 * 256)  hzwb[tid] = f2b(hzw[tid]);
  if (tid < 256 * 256)  outwb[tid] = f2b(outw[tid]);
}

// ---------------------------------------------------------------------------
// K1: depthwise 3x3 conv (zero pad), fp32 input -> per-channel sum/sumsq
__global__ __launch_bounds__(256) void k_conv_stats(
    const float* __restrict__ x, const float* __restrict__ w,
    float* __restrict__ bnsum, float* __restrict__ bnsq){
  __shared__ float t[66 * 66];
  __shared__ float rs[4], rq[4];
  int bc = blockIdx.x; int c = bc & 255;
  const float* xp = x + (size_t)bc * 4096;
  int tid = threadIdx.x;
  for (int i = tid; i < 66 * 66; i += 256) t[i] = 0.f;
  __syncthreads();
  #pragma unroll
  for (int j = 0; j < 4; j++){
    int p4 = tid + j * 256;
    float4 v = reinterpret_cast<const float4*>(xp)[p4];
    int p = p4 * 4; int y = p >> 6, xx = p & 63;
    int base = (y + 1) * 66 + xx + 1;
    t[base] = v.x; t[base + 1] = v.y; t[base + 2] = v.z; t[base + 3] = v.w;
  }
  __syncthreads();
  float w0 = w[c*9+0], w1 = w[c*9+1], w2 = w[c*9+2], w3 = w[c*9+3], w4 = w[c*9+4];
  float w5 = w[c*9+5], w6 = w[c*9+6], w7 = w[c*9+7], w8 = w[c*9+8];
  float s = 0.f, q = 0.f;
  #pragma unroll
  for (int j = 0; j < 16; j++){
    int p = tid + j * 256; int y = p >> 6, xx = p & 63;
    const float* r0 = &t[y * 66 + xx];
    float v = r0[0]*w0 + r0[1]*w1 + r0[2]*w2 + r0[66]*w3 + r0[67]*w4 + r0[68]*w5
            + r0[132]*w6 + r0[133]*w7 + r0[134]*w8;
    s += v; q += v * v;
  }
  #pragma unroll
  for (int off = 32; off > 0; off >>= 1){ s += __shfl_down(s, off); q += __shfl_down(q, off); }
  if ((tid & 63) == 0){ rs[tid >> 6] = s; rq[tid >> 6] = q; }
  __syncthreads();
  if (tid == 0){
    atomicAdd(&bnsum[c], rs[0] + rs[1] + rs[2] + rs[3]);
    atomicAdd(&bnsq[c],  rq[0] + rq[1] + rq[2] + rq[3]);
  }
}

// K1h: same, bf16 input (residual chain)
__global__ __launch_bounds__(256) void k_conv_stats_h(
    const unsigned short* __restrict__ x, const float* __restrict__ w,
    float* __restrict__ bnsum, float* __restrict__ bnsq){
  __shared__ float t[66 * 66];
  __shared__ float rs[4], rq[4];
  int bc = blockIdx.x; int c = bc & 255;
  const unsigned short* xp = x + (size_t)bc * 4096;
  int tid = threadIdx.x;
  for (int i = tid; i < 66 * 66; i += 256) t[i] = 0.f;
  __syncthreads();
  #pragma unroll
  for (int j = 0; j < 2; j++){
    int p8 = tid + j * 256;
    unsigned short vv[8];
    *reinterpret_cast<uint4*>(vv) = reinterpret_cast<const uint4*>(xp)[p8];
    int p = p8 * 8; int y = p >> 6, xx = p & 63;
    int base = (y + 1) * 66 + xx + 1;
    #pragma unroll
    for (int k = 0; k < 8; k++) t[base + k] = b2f(vv[k]);
  }
  __syncthreads();
  float w0 = w[c*9+0], w1 = w[c*9+1], w2 = w[c*9+2], w3 = w[c*9+3], w4 = w[c*9+4];
  float w5 = w[c*9+5], w6 = w[c*9+6], w7 = w[c*9+7], w8 = w[c*9+8];
  float s = 0.f, q = 0.f;
  #pragma unroll
  for (int j = 0; j < 16; j++){
    int p = tid + j * 256; int y = p >> 6, xx = p & 63;
    const float* r0 = &t[y * 66 + xx];
    float v = r0[0]*w0 + r0[1]*w1 + r0[2]*w2 + r0[66]*w3 + r0[67]*w4 + r0[68]*w5
            + r0[132]*w6 + r0[133]*w7 + r0[134]*w8;
    s += v; q += v * v;
  }
  #pragma unroll
  for (int off = 32; off > 0; off >>= 1){ s += __shfl_down(s, off); q += __shfl_down(q, off); }
  if ((tid & 63) == 0){ rs[tid >> 6] = s; rq[tid >> 6] = q; }
  __syncthreads();
  if (tid == 0){
    atomicAdd(&bnsum[c], rs[0] + rs[1] + rs[2] + rs[3]);
    atomicAdd(&bnsq[c],  rq[0] + rq[1] + rq[2] + rq[3]);
  }
}

// K2a: x1 = (1-a)*x + a*BN(conv(x)), fp32 in -> bf16 out
__global__ __launch_bounds__(256) void k_conv_bn_blend_f2h(
    const float* __restrict__ x, const float* __restrict__ w,
    const float* __restrict__ bnsum, const float* __restrict__ bnsq,
    const float* __restrict__ g, const float* __restrict__ bb,
    const float* __restrict__ alpha, unsigned short* __restrict__ out){
  __shared__ float t[66 * 66];
  int bc = blockIdx.x; int c = bc & 255;
  const float* xp = x + (size_t)bc * 4096;
  unsigned short* op = out + (size_t)bc * 4096;
  int tid = threadIdx.x;
  for (int i = tid; i < 66 * 66; i += 256) t[i] = 0.f;
  __syncthreads();
  #pragma unroll
  for (int j = 0; j < 4; j++){
    int p4 = tid + j * 256;
    float4 v = reinterpret_cast<const float4*>(xp)[p4];
    int p = p4 * 4; int y = p >> 6, xx = p & 63;
    int base = (y + 1) * 66 + xx + 1;
    t[base] = v.x; t[base + 1] = v.y; t[base + 2] = v.z; t[base + 3] = v.w;
  }
  __syncthreads();
  float w0 = w[c*9+0], w1 = w[c*9+1], w2 = w[c*9+2], w3 = w[c*9+3], w4 = w[c*9+4];
  float w5 = w[c*9+5], w6 = w[c*9+6], w7 = w[c*9+7], w8 = w[c*9+8];
  float m  = bnsum[c] * (1.f / 65536.f);
  float var = bnsq[c] * (1.f / 65536.f) - m * m;
  float sc = rsqrtf(var + 1e-5f) * g[c];
  float bias = bb[c];
  float a = sigm(alpha[c]);
  #pragma unroll
  for (int j = 0; j < 16; j++){
    int p = tid + j * 256; int y = p >> 6, xx = p & 63;
    const float* r0 = &t[y * 66 + xx];
    float v = r0[0]*w0 + r0[1]*w1 + r0[2]*w2 + r0[66]*w3 + r0[67]*w4 + r0[68]*w5
            + r0[132]*w6 + r0[133]*w7 + r0[134]*w8;
    float xv = t[(y + 1) * 66 + xx + 1];
    op[p] = f2b((1.f - a) * xv + a * ((v - m) * sc + bias));
  }
}

// K2b: x3 = (1-a)*x2 + a*BN2(conv(x2)), bf16 in -> bf16 out (in-place ok)
__global__ __launch_bounds__(256) void k_conv_bn_blend_h2h(
    const unsigned short* __restrict__ x, const float* __restrict__ w,
    const float* __restrict__ bnsum, const float* __restrict__ bnsq,
    const float* __restrict__ g, const float* __restrict__ bb,
    const float* __restrict__ alpha, unsigned short* __restrict__ out){
  __shared__ float t[66 * 66];
  int bc = blockIdx.x; int c = bc & 255;
  const unsigned short* xp = x + (size_t)bc * 4096;
  unsigned short* op = out + (size_t)bc * 4096;
  int tid = threadIdx.x;
  for (int i = tid; i < 66 * 66; i += 256) t[i] = 0.f;
  __syncthreads();
  #pragma unroll
  for (int j = 0; j < 2; j++){
    int p8 = tid + j * 256;
    unsigned short vv[8];
    *reinterpret_cast<uint4*>(vv) = reinterpret_cast<const uint4*>(xp)[p8];
    int p = p8 * 8; int y = p >> 6, xx = p & 63;
    int base = (y + 1) * 66 + xx + 1;
    #pragma unroll
    for (int k = 0; k < 8; k++) t[base + k] = b2f(vv[k]);
  }
  __syncthreads();
  float w0 = w[c*9+0], w1 = w[c*9+1], w2 = w[c*9+2], w3 = w[c*9+3], w4 = w[c*9+4];
  float w5 = w[c*9+5], w6 = w[c*9+6], w7 = w[c*9+7], w8 = w[c*9+8];
  float m  = bnsum[c] * (1.f / 65536.f);
  float var = bnsq[c] * (1.f / 65536.f) - m * m;
  float sc = rsqrtf(var + 1e-5f) * g[c];
  float bias = bb[c];
  float a = sigm(alpha[c]);
  #pragma unroll
  for (int j = 0; j < 16; j++){
    int p = tid + j * 256; int y = p >> 6, xx = p & 63;
    const float* r0 = &t[y * 66 + xx];
    float v = r0[0]*w0 + r0[1]*w1 + r0[2]*w2 + r0[66]*w3 + r0[67]*w4 + r0[68]*w5
            + r0[132]*w6 + r0[133]*w7 + r0[134]*w8;
    float xv = t[(y + 1) * 66 + xx + 1];
    op[p] = f2b((1.f - a) * xv + a * ((v - m) * sc + bias));
  }
}

// ---------------------------------------------------------------------------
// K2c: per-pixel LayerNorm over C (bf16 xres in) -> xf (b,c,l) + xfT (b,l,c)
__global__ __launch_bounds__(256) void k_ln(
    const unsigned short* __restrict__ x1, const float* __restrict__ lnw,
    const float* __restrict__ lnb, unsigned short* __restrict__ xf,
    unsigned short* __restrict__ xfT){
  __shared__ unsigned short st[256 * 65];            // [c][pixel], pad 65
  __shared__ float reds[4][64], redq[4][64];
  int b = blockIdx.x >> 6, lt = blockIdx.x & 63; int l0 = lt * 64;
  int t = threadIdx.x, w = t >> 6, lane = t & 63;
  const unsigned short* xp = x1 + ((size_t)b * 256) * 4096 + l0 + lane;
  float s = 0.f, q = 0.f;
  for (int i = 0; i < 64; i++){
    int c = w * 64 + i;
    unsigned short h = xp[(size_t)c * 4096];
    float v = b2f(h);
    s += v; q += v * v;
    st[c * 65 + lane] = h;
  }
  reds[w][lane] = s; redq[w][lane] = q;
  __syncthreads();
  s = reds[0][lane] + reds[1][lane] + reds[2][lane] + reds[3][lane];
  q = redq[0][lane] + redq[1][lane] + redq[2][lane] + redq[3][lane];
  float m = s * (1.f / 256.f);
  float r = rsqrtf(q * (1.f / 256.f) - m * m + 1e-5f);
  for (int i = 0; i < 64; i++){
    int c = w * 64 + i;
    float v = b2f(st[c * 65 + lane]);
    unsigned short h = f2b((v - m) * r * lnw[c] + lnb[c]);
    st[c * 65 + lane] = h;
    xf[((size_t)(b * 256 + c)) * 4096 + l0 + lane] = h;
  }
  __syncthreads();
  int p = t >> 4, cc = t & 15;                       // 16 lanes per pixel row
  for (int pi = 0; pi < 4; pi++){
    int px = p + pi * 16;
    #pragma unroll
    for (int j = 0; j < 2; j++){
      int c0 = (j * 16 + cc) * 8;
      unsigned short vv[8];
      #pragma unroll
      for (int k = 0; k < 8; k++) vv[k] = st[(c0 + k) * 65 + px];
      *reinterpret_cast<uint4*>(&xfT[((size_t)(b * 4096 + l0 + px)) * 256 + c0]) =
          *reinterpret_cast<uint4*>(vv);
    }
  }
}

// K2d: x3 bf16 (b,c,l) -> x3T bf16 (b,l,c)
__global__ __launch_bounds__(256) void k_xt(
    const unsigned short* __restrict__ x, unsigned short* __restrict__ xT){
  __shared__ unsigned short st[256 * 65];
  int b = blockIdx.x >> 6, lt = blockIdx.x & 63; int l0 = lt * 64;
  int t = threadIdx.x, w = t >> 6, lane = t & 63;
  const unsigned short* xp = x + ((size_t)b * 256) * 4096 + l0 + lane;
  for (int i = 0; i < 64; i++){
    int c = w * 64 + i;
    st[c * 65 + lane] = xp[(size_t)c * 4096];
  }
  __syncthreads();
  int p = t >> 4, cc = t & 15;
  for (int pi = 0; pi < 4; pi++){
    int px = p + pi * 16;
    #pragma unroll
    for (int j = 0; j < 2; j++){
      int c0 = (j * 16 + cc) * 8;
      unsigned short vv[8];
      #pragma unroll
      for (int k = 0; k < 8; k++) vv[k] = st[(c0 + k) * 65 + px];
      *reinterpret_cast<uint4*>(&xT[((size_t)(b * 4096 + l0 + px)) * 256 + c0]) =
          *reinterpret_cast<uint4*>(vv);
    }
  }
}

// ---------------------------------------------------------------------------
// K3: BCdt = bcdt_w(192x256) @ xf + bias  (MFMA, operands direct from global)
__global__ __launch_bounds__(256) void k_bcdt(
    const unsigned short* __restrict__ xfT, const unsigned short* __restrict__ wb,
    const float* __restrict__ bias, unsigned short* __restrict__ outp){
  int blk = blockIdx.x; int b = blk >> 6, lt = blk & 63; int l0 = lt * 64;
  int t = threadIdx.x; int wv = t >> 6, lane = t & 63;
  int col = lane & 15, g = lane >> 4;
  f32x4 acc[3][4];
  #pragma unroll
  for (int mm = 0; mm < 3; mm++)
    #pragma unroll
    for (int nn = 0; nn < 4; nn++) acc[mm][nn] = zero4();
  for (int k = 0; k < 8; k++){
    bf16x8 av[3], bv[4];
    #pragma unroll
    for (int mm = 0; mm < 3; mm++){
      int o = (wv * 3 + mm) * 16 + col;
      av[mm] = ldb8g(&wb[(size_t)o * 256 + k * 32 + g * 8]);
    }
    #pragma unroll
    for (int nn = 0; nn < 4; nn++){
      int l = l0 + nn * 16 + col;
      bv[nn] = ldb8g(&xfT[((size_t)(b * 4096 + l)) * 256 + k * 32 + g * 8]);
    }
    #pragma unroll
    for (int mm = 0; mm < 3; mm++)
      #pragma unroll
      for (int nn = 0; nn < 4; nn++) acc[mm][nn] = mfma16(av[mm], bv[nn], acc[mm][nn]);
  }
  #pragma unroll
  for (int mm = 0; mm < 3; mm++)
    #pragma unroll
    for (int nn = 0; nn < 4; nn++)
      #pragma unroll
      for (int r = 0; r < 4; r++){
        int o = (wv * 3 + mm) * 16 + g * 4 + r;
        int l = l0 + nn * 16 + col;
        outp[((size_t)(b * 192 + o)) * 4096 + l] = f2b(acc[mm][nn][r] + bias[o]);
      }
}

// ---------------------------------------------------------------------------
// K4: depthwise conv on BCdt (192 ch) + bias; dt channels also reduce softmax
// stats (max & sumexp over the full 4096-pixel plane == softmax row).
__global__ __launch_bounds__(256) void k_conv_mid(
    const unsigned short* __restrict__ in, const float* __restrict__ w,
    const float* __restrict__ wbias, unsigned short* __restrict__ outp,
    float* __restrict__ smmax, float* __restrict__ smsum){
  __shared__ float t[66 * 66];
  __shared__ float red[8];
  int blk = blockIdx.x; int b = blk / 192, ch = blk % 192;
  const unsigned short* xp = in + (size_t)blk * 4096;
  unsigned short* op = outp + (size_t)blk * 4096;
  int tid = threadIdx.x;
  for (int i = tid; i < 66 * 66; i += 256) t[i] = 0.f;
  __syncthreads();
  #pragma unroll
  for (int j = 0; j < 2; j++){
    int p8 = tid + j * 256;
    unsigned short vv[8];
    *reinterpret_cast<uint4*>(vv) = reinterpret_cast<const uint4*>(xp)[p8];
    int p = p8 * 8; int y = p >> 6, xx = p & 63;
    int base = (y + 1) * 66 + xx + 1;
    #pragma unroll
    for (int k = 0; k < 8; k++) t[base + k] = b2f(vv[k]);
  }
  __syncthreads();
  float w0 = w[ch*9+0], w1 = w[ch*9+1], w2 = w[ch*9+2], w3 = w[ch*9+3], w4 = w[ch*9+4];
  float w5 = w[ch*9+5], w6 = w[ch*9+6], w7 = w[ch*9+7], w8 = w[ch*9+8];
  float bv = wbias[ch];
  float vloc[16];
  float mx = -1e30f;
  #pragma unroll
  for (int j = 0; j < 16; j++){
    int p = tid + j * 256; int y = p >> 6, xx = p & 63;
    const float* r0 = &t[y * 66 + xx];
    float v = r0[0]*w0 + r0[1]*w1 + r0[2]*w2 + r0[66]*w3 + r0[67]*w4 + r0[68]*w5
            + r0[132]*w6 + r0[133]*w7 + r0[134]*w8 + bv;
    unsigned short h = f2b(v);
    op[p] = h;
    float vb = b2f(h);
    vloc[j] = vb;
    mx = fmaxf(mx, vb);
  }
  if (ch >= 128){                                    // dt channel: softmax stats
    #pragma unroll
    for (int off = 32; off > 0; off >>= 1) mx = fmaxf(mx, __shfl_down(mx, off));
    if ((tid & 63) == 0) red[tid >> 6] = mx;
    __syncthreads();
    float M = fmaxf(fmaxf(red[0], red[1]), fmaxf(red[2], red[3]));
    float se = 0.f;
    #pragma unroll
    for (int j = 0; j < 16; j++) se += __expf(vloc[j] - M);
    #pragma unroll
    for (int off = 32; off > 0; off >>= 1) se += __shfl_down(se, off);
    if ((tid & 63) == 0) red[4 + (tid >> 6)] = se;
    __syncthreads();
    if (tid == 0){
      smmax[b * 64 + ch - 128] = M;
      smsum[b * 64 + ch - 128] = red[4] + red[5] + red[6] + red[7];
    }
  }
}

// K5 (merged): blocks 0..1023: AB = softmax(dt)*Bm; blocks 1024..2047: CmT.
__global__ __launch_bounds__(256) void k_ab_cmt(
    const unsigned short* __restrict__ bc, const float* __restrict__ smmax,
    const float* __restrict__ smsum, unsigned short* __restrict__ ab,
    unsigned short* __restrict__ cmt){
  __shared__ float t[64 * 65];
  int blk = blockIdx.x;
  if (blk < 1024){
    int b = blk >> 6, s = blk & 63;
    const unsigned short* dt = bc + ((size_t)(b * 192 + 128 + s)) * 4096;
    const unsigned short* bm = bc + ((size_t)(b * 192 + s)) * 4096;
    unsigned short* o = ab + ((size_t)(b * 64 + s)) * 4096;
    float M = smmax[b * 64 + s];
    float inv = 1.f / smsum[b * 64 + s];
    for (int i = threadIdx.x; i < 4096; i += 256)
      o[i] = f2b(__expf(b2f(dt[i]) - M) * inv * b2f(bm[i]));
    return;
  }
  blk -= 1024;
  int b = blk >> 6, lt = blk & 63; int l0 = lt * 64;
  int tid = threadIdx.x;
  #pragma unroll
  for (int it = 0; it < 2; it++){
    int row = (tid >> 3) + it * 32;                  // s
    int lq = (tid & 7) * 8;
    const unsigned short* p = bc + ((size_t)(b * 192 + 64 + row)) * 4096 + l0 + lq;
    unsigned short vv[8];
    *reinterpret_cast<uint4*>(vv) = *reinterpret_cast<const uint4*>(p);
    #pragma unroll
    for (int k = 0; k < 8; k++) t[row * 65 + lq + k] = b2f(vv[k]);
  }
  __syncthreads();
  #pragma unroll
  for (int it = 0; it < 2; it++){
    int l = (tid >> 3) + it * 32;
    int sq = (tid & 7) * 8;
    unsigned short vv[8];
    #pragma unroll
    for (int k = 0; k < 8; k++) vv[k] = f2b(t[(sq + k) * 65 + l]);
    *reinterpret_cast<uint4*>(&cmt[((size_t)(b * 4096 + l0 + l)) * 64 + sq]) =
        *reinterpret_cast<uint4*>(vv);
  }
}

// ---------------------------------------------------------------------------
// K6: hT[b,s,c] += sum_l AB[s,l]*xf[c,l]  -- 16 K-chunks over l, grid 256
__global__ __launch_bounds__(512) void k_h(
    const unsigned short* __restrict__ ab, const unsigned short* __restrict__ xf,
    float* __restrict__ hpart){
  int blk = blockIdx.x; int b = blk & 15, chunk = blk >> 4;   // grid 256
  int t = threadIdx.x; int wv = t >> 6, lane = t & 63;
  int col = lane & 15, g = lane >> 4;
  int mt = wv & 3, nh = wv >> 2;
  f32x4 acc[8];
  #pragma unroll
  for (int nn = 0; nn < 8; nn++) acc[nn] = zero4();
  int lbase = chunk * 256;
  const unsigned short* ap = ab + ((size_t)(b * 64 + mt * 16 + col)) * 4096 + lbase + g * 8;
  for (int ks = 0; ks < 8; ks++){
    bf16x8 av = ldb8g(ap + ks * 32);
    #pragma unroll
    for (int nn = 0; nn < 8; nn++){
      int c = nh * 128 + nn * 16 + col;
      bf16x8 bv = ldb8g(&xf[((size_t)(b * 256 + c)) * 4096 + lbase + ks * 32 + g * 8]);
      acc[nn] = mfma16(av, bv, acc[nn]);
    }
  }
  #pragma unroll
  for (int nn = 0; nn < 8; nn++)
    #pragma unroll
    for (int r = 0; r < 4; r++){
      int s = mt * 16 + g * 4 + r;
      int c = nh * 128 + nn * 16 + col;
      hpart[(((size_t)chunk * 16 + b) * 64 + s) * 256 + c] = acc[nn][r];
    }
}

// K7pre: sum 16 k-partials -> bf16 [b][s][c]
__global__ __launch_bounds__(256) void k_hsum(
    const float* __restrict__ hp, unsigned short* __restrict__ hsb){
  int i = blockIdx.x * 256 + threadIdx.x;            // 262144
  float s = 0.f;
  #pragma unroll
  for (int c = 0; c < 16; c++) s += hp[(size_t)c * 262144 + i];
  hsb[i] = f2b(s);
}

// K7a (MFMA): u = hzw @ h + hzb; hh1 = u * (silu(z) + D)  -> bf16 [b][s][o]
__global__ __launch_bounds__(256) void k_hz(
    const unsigned short* __restrict__ hsb, const unsigned short* __restrict__ hzwb,
    const float* __restrict__ hzb, const float* __restrict__ Dp,
    unsigned short* __restrict__ hh1b){
  int blk = blockIdx.x; int b = blk >> 2, og = blk & 3;
  int t = threadIdx.x, wv = t >> 6, lane = t & 63;
  int col = lane & 15, g = lane >> 4;
  int ou = og * 64 + wv * 16;                        // u-row base (0..255)
  int oz = 256 + ou;                                 // paired z-row
  f32x4 au[4], az[4];
  #pragma unroll
  for (int nn = 0; nn < 4; nn++){ au[nn] = zero4(); az[nn] = zero4(); }
  const unsigned short* bbase = hsb + (size_t)b * 64 * 256;
  for (int k = 0; k < 8; k++){
    bf16x8 a_u = ldb8g(&hzwb[(size_t)(ou + col) * 256 + k * 32 + g * 8]);
    bf16x8 a_z = ldb8g(&hzwb[(size_t)(oz + col) * 256 + k * 32 + g * 8]);
    bf16x8 bv[4];
    #pragma unroll
    for (int nn = 0; nn < 4; nn++)
      bv[nn] = ldb8g(bbase + (size_t)(nn * 16 + col) * 256 + k * 32 + g * 8);
    #pragma unroll
    for (int nn = 0; nn < 4; nn++){
      au[nn] = mfma16(a_u, bv[nn], au[nn]);
      az[nn] = mfma16(a_z, bv[nn], az[nn]);
    }
  }
  float Dv = Dp[0];
  #pragma unroll
  for (int nn = 0; nn < 4; nn++){
    int s = nn * 16 + col;
    float hv[4];
    #pragma unroll
    for (int r = 0; r < 4; r++){
      int o = ou + g * 4 + r;
      float u = au[nn][r] + hzb[o];
      float z = az[nn][r] + hzb[o + 256];
      float sl = z / (1.f + __expf(-z));
      hv[r] = u * (sl + Dv);
    }
    unsigned int p0 = cvtpk(hv[0], hv[1]), p1 = cvtpk(hv[2], hv[3]);
    uint2 pv; pv.x = p0; pv.y = p1;
    *reinterpret_cast<uint2*>(&hh1b[((size_t)(b * 64 + s)) * 256 + ou + g * 4]) = pv;
  }
}

// K7b (MFMA): hh2[b][d][s] = outw @ hh1 + out_b  (bf16)
__global__ __launch_bounds__(256) void k_out(
    const unsigned short* __restrict__ hh1b, const unsigned short* __restrict__ outwb,
    const float* __restrict__ ob, unsigned short* __restrict__ hh2){
  int blk = blockIdx.x; int b = blk >> 2, dg = blk & 3;
  int t = threadIdx.x, wv = t >> 6, lane = t & 63;
  int col = lane & 15, g = lane >> 4;
  int d0 = dg * 64 + wv * 16;
  f32x4 acc[4];
  #pragma unroll
  for (int nn = 0; nn < 4; nn++) acc[nn] = zero4();
  const unsigned short* bbase = hh1b + (size_t)b * 64 * 256;
  for (int k = 0; k < 8; k++){
    bf16x8 a = ldb8g(&outwb[(size_t)(d0 + col) * 256 + k * 32 + g * 8]);
    bf16x8 bv[4];
    #pragma unroll
    for (int nn = 0; nn < 4; nn++)
      bv[nn] = ldb8g(bbase + (size_t)(nn * 16 + col) * 256 + k * 32 + g * 8);
    #pragma unroll
    for (int nn = 0; nn < 4; nn++) acc[nn] = mfma16(a, bv[nn], acc[nn]);
  }
  #pragma unroll
  for (int nn = 0; nn < 4; nn++){
    int s = nn * 16 + col;
    #pragma unroll
    for (int r = 0; r < 4; r++){
      int d = d0 + g * 4 + r;
      hh2[((size_t)(b * 256 + d)) * 64 + s] = f2b(acc[nn][r] + ob[d]);
    }
  }
}

// K8: y = hh2 @ Cm ; x2 = (1-a1)*x1 + a1*y  (in-place on bf16 xres)
__global__ __launch_bounds__(256) void k_y_blend(
    const unsigned short* __restrict__ hh2, const unsigned short* __restrict__ cmt,
    const float* __restrict__ alpha, unsigned short* __restrict__ x){
  int blk = blockIdx.x; int b = blk >> 6, lt = blk & 63; int l0 = lt * 64;
  int t = threadIdx.x; int wv = t >> 6, lane = t & 63;
  int col = lane & 15, g = lane >> 4;
  f32x4 acc[4][4];
  #pragma unroll
  for (int mm = 0; mm < 4; mm++)
    #pragma unroll
    for (int nn = 0; nn < 4; nn++) acc[mm][nn] = zero4();
  #pragma unroll
  for (int k = 0; k < 2; k++){
    bf16x8 av[4], bv[4];
    #pragma unroll
    for (int mm = 0; mm < 4; mm++){
      int c = (wv * 4 + mm) * 16 + col;
      av[mm] = ldb8g(&hh2[((size_t)(b * 256 + c)) * 64 + k * 32 + g * 8]);
    }
    #pragma unroll
    for (int nn = 0; nn < 4; nn++){
      int l = l0 + nn * 16 + col;
      bv[nn] = ldb8g(&cmt[((size_t)(b * 4096 + l)) * 64 + k * 32 + g * 8]);
    }
    #pragma unroll
    for (int mm = 0; mm < 4; mm++)
      #pragma unroll
      for (int nn = 0; nn < 4; nn++) acc[mm][nn] = mfma16(av[mm], bv[nn], acc[mm][nn]);
  }
  #pragma unroll
  for (int mm = 0; mm < 4; mm++)
    #pragma unroll
    for (int r = 0; r < 4; r++){
      int c = (wv * 4 + mm) * 16 + g * 4 + r;
      float a1 = sigm(alpha[c]);
      #pragma unroll
      for (int nn = 0; nn < 4; nn++){
        int l = l0 + nn * 16 + col;
        size_t idx = ((size_t)(b * 256 + c)) * 4096 + l;
        float xv = b2f(x[idx]);
        x[idx] = f2b((1.f - a1) * xv + a1 * acc[mm][nn][r]);
      }
    }
}

// ---------------------------------------------------------------------------
// K11a: H[l][o] = gelu(W1 @ x3 + b1) for one batch-half (m97 structure).
// XCD-swizzled; cheap-gelu + cvt_pk epilogue; padded-136 bounce.
__global__ __launch_bounds__(256, 4) void k_ffn1(
    const unsigned short* __restrict__ xT, const unsigned short* __restrict__ w1b,
    const float* __restrict__ b1, unsigned short* __restrict__ Hh, int b0){
  __shared__ unsigned short smem[17408];             // max(A+B 32KB, bounce 34KB)
  unsigned short* At = smem;                         // [128][64]
  unsigned short* Bt = smem + 8192;                  // [128][64]
  int wk = ((blockIdx.x & 7) << 8) + (blockIdx.x >> 3);   // bijective XCD swizzle
  int mt = wk & 7, nt = wk >> 3;
  int t = threadIdx.x, wv = t >> 6, lane = t & 63;
  int col = lane & 15, g = lane >> 4;
  int wr = wv >> 1, wc = wv & 1;
  const unsigned short* ag = w1b + (size_t)(mt * 128) * 256;
  const unsigned short* bg = xT + ((size_t)b0 * 4096 + (size_t)nt * 128) * 256;
  float bias[4][4];
  #pragma unroll
  for (int mm = 0; mm < 4; mm++)
    #pragma unroll
    for (int r = 0; r < 4; r++)
      bias[mm][r] = b1[mt * 128 + wr * 64 + mm * 16 + g * 4 + r];
  f32x4 acc[4][4];
  #pragma unroll
  for (int mm = 0; mm < 4; mm++)
    #pragma unroll
    for (int nn = 0; nn < 4; nn++) acc[mm][nn] = zero4();
  for (int kk = 0; kk < 4; kk++){
    __syncthreads();
    #pragma unroll
    for (int j = 0; j < 4; j++){
      int id = t + j * 256;                          // 0..1023
      int row = id >> 3, kc = (id & 7) * 8;
      gload_lds16(ag + (size_t)row * 256 + kk * 64 + kc, At + id * 8);
      gload_lds16(bg + (size_t)row * 256 + kk * 64 + kc, Bt + id * 8);
    }
    __syncthreads();
    #pragma unroll
    for (int ks = 0; ks < 2; ks++){
      bf16x8 av[4], bv[4];
      #pragma unroll
      for (int mm = 0; mm < 4; mm++)
        av[mm] = *reinterpret_cast<const bf16x8*>(&At[(wr * 64 + mm * 16 + col) * 64 + ks * 32 + g * 8]);
      #pragma unroll
      for (int nn = 0; nn < 4; nn++)
        bv[nn] = *reinterpret_cast<const bf16x8*>(&Bt[(wc * 64 + nn * 16 + col) * 64 + ks * 32 + g * 8]);
      #pragma unroll
      for (int mm = 0; mm < 4; mm++)
        #pragma unroll
        for (int nn = 0; nn < 4; nn++)
          acc[mm][nn] = mfma16(av[mm], bv[nn], acc[mm][nn]);
    }
  }
  __syncthreads();
  // cheap gelu -> cvt_pk -> bounce [128 l][136 o-pad]
  #pragma unroll
  for (int mm = 0; mm < 4; mm++){
    int o4 = wr * 64 + mm * 16 + g * 4;
    #pragma unroll
    for (int nn = 0; nn < 4; nn++){
      int lloc = wc * 64 + nn * 16 + col;
      float gv[4];
      #pragma unroll
      for (int r = 0; r < 4; r++)
        gv[r] = gelu_fast(acc[mm][nn][r] + bias[mm][r]);
      uint2 pv; pv.x = cvtpk(gv[0], gv[1]); pv.y = cvtpk(gv[2], gv[3]);
      *reinterpret_cast<uint2*>(&smem[lloc * 136 + o4]) = pv;
    }
  }
  __syncthreads();
  size_t hb = (size_t)nt * 128;
  #pragma unroll
  for (int j = 0; j < 8; j++){
    int id = t + j * 256;                            // 0..2047
    int l = id >> 4, oc = id & 15;
    uint4 v = *reinterpret_cast<const uint4*>(&smem[l * 136 + oc * 8]);
    *reinterpret_cast<uint4*>(&Hh[(hb + l) * 1024 + mt * 128 + oc * 8]) = v;
  }
}

// K11b: out_fp32 = (1-a3)*x3(bf16) + a3*(W2 @ H + b2) for one batch-half.
// 128d x 64l tile, grid 1024/half, 4 blocks/CU, single-buffered (optimum).
__global__ __launch_bounds__(256, 4) void k_ffn2(
    const unsigned short* __restrict__ Hh, const unsigned short* __restrict__ w2b,
    const float* __restrict__ b2, const float* __restrict__ alpha3,
    const unsigned short* __restrict__ xres, float* __restrict__ outp, int b0){
  __shared__ unsigned short At[128 * 64];            // 16KB
  __shared__ unsigned short Bt[64 * 64];             // 8KB
  int wk = ((blockIdx.x & 7) << 7) + (blockIdx.x >> 3);   // bijective XCD swizzle
  int mt = wk & 1, nt = wk >> 1;                     // nt 0..511 (64-px tiles)
  int t = threadIdx.x, wv = t >> 6, lane = t & 63;
  int col = lane & 15, g = lane >> 4;
  int wr = wv >> 1, wc = wv & 1;                     // wave: 64d x 32l
  const unsigned short* ag = w2b + (size_t)(mt * 128) * 1024;
  const unsigned short* bg = Hh + (size_t)(nt * 64) * 1024;
  f32x4 acc[4][2];
  #pragma unroll
  for (int mm = 0; mm < 4; mm++)
    #pragma unroll
    for (int nn = 0; nn < 2; nn++) acc[mm][nn] = zero4();
  for (int kk = 0; kk < 16; kk++){
    __syncthreads();
    #pragma unroll
    for (int j = 0; j < 4; j++){                     // A: 1024 x 16B
      int id = t + j * 256;
      int row = id >> 3, kc = (id & 7) * 8;
      gload_lds16(ag + (size_t)row * 1024 + kk * 64 + kc, At + id * 8);
    }
    #pragma unroll
    for (int j = 0; j < 2; j++){                     // B: 512 x 16B
      int id = t + j * 256;
      int row = id >> 3, kc = (id & 7) * 8;
      gload_lds16(bg + (size_t)row * 1024 + kk * 64 + kc, Bt + id * 8);
    }
    __syncthreads();
    #pragma unroll
    for (int ks = 0; ks < 2; ks++){
      bf16x8 av[4], bv[2];
      #pragma unroll
      for (int mm = 0; mm < 4; mm++)
        av[mm] = *reinterpret_cast<const bf16x8*>(&At[(wr * 64 + mm * 16 + col) * 64 + ks * 32 + g * 8]);
      #pragma unroll
      for (int nn = 0; nn < 2; nn++)
        bv[nn] = *reinterpret_cast<const bf16x8*>(&Bt[(wc * 32 + nn * 16 + col) * 64 + ks * 32 + g * 8]);
      #pragma unroll
      for (int mm = 0; mm < 4; mm++)
        #pragma unroll
        for (int nn = 0; nn < 2; nn++)
          acc[mm][nn] = mfma16(av[mm], bv[nn], acc[mm][nn]);
    }
  }
  #pragma unroll
  for (int mm = 0; mm < 4; mm++)
    #pragma unroll
    for (int r = 0; r < 4; r++){
      int d = mt * 128 + wr * 64 + mm * 16 + g * 4 + r;
      float a3 = sigm(alpha3[d]);
      float bias = b2[d];
      #pragma unroll
      for (int nn = 0; nn < 2; nn++){
        int lh = nt * 64 + wc * 32 + nn * 16 + col;
        int b = b0 + (lh >> 12);
        int l = lh & 4095;
        size_t idx = ((size_t)(b * 256 + d)) * 4096 + l;
        float xv = b2f(xres[idx]);
        outp[idx] = (1.f - a3) * xv + a3 * (acc[mm][nn][r] + bias);
      }
    }
}

// ---------------------------------------------------------------------------
extern "C" void kernel_launch(void* const* d_in, const int* in_sizes, int n_in,
                              void* d_out, int out_size, void* d_ws, size_t ws_size,
                              hipStream_t stream){
  (void)in_sizes; (void)n_in; (void)out_size; (void)ws_size;
  const float* x      = (const float*)d_in[0];
  const float* alpha  = (const float*)d_in[1];
  const float* dw1_w  = (const float*)d_in[2];
  const float* bn1_g  = (const float*)d_in[3];
  const float* bn1_b  = (const float*)d_in[4];
  const float* dw2_w  = (const float*)d_in[5];
  const float* bn2_g  = (const float*)d_in[6];
  const float* bn2_b  = (const float*)d_in[7];
  const float* ln_w   = (const float*)d_in[8];
  const float* ln_b   = (const float*)d_in[9];
  const float* bcdt_w = (const float*)d_in[10];
  const float* bcdt_b = (const float*)d_in[11];
  const float* mdw_w  = (const float*)d_in[12];
  const float* mdw_b  = (const float*)d_in[13];
  const float* hz_w   = (const float*)d_in[14];
  const float* hz_b   = (const float*)d_in[15];
  const float* out_w  = (const float*)d_in[16];
  const float* out_b  = (const float*)d_in[17];
  // d_in[18] = A: cancels exactly in softmax over L (constant shift per row)
  const float* Dvec   = (const float*)d_in[19];
  const float* ffn_w1 = (const float*)d_in[20];
  const float* ffn_b1 = (const float*)d_in[21];
  const float* ffn_w2 = (const float*)d_in[22];
  const float* ffn_b2 = (const float*)d_in[23];
  float* out = (float*)d_out;
  char* ws = (char*)d_ws;

  // ---- ws map (bf16 residual chain; lifetimes audited, R15 layout) ----
  const size_t OFF_XRES  = 0;
  const size_t OFF_XF    = 33554432;
  const size_t OFF_XFT   = 67108864;
  const size_t OFF_BCC   = 67108864;
  const size_t OFF_BCRAW = 100663296;
  const size_t OFF_AB    = 100663296;
  const size_t OFF_CMT   = 109051904;
  const size_t OFF_HPART = 117440512;
  const size_t OFF_X3T   = 33554432;
  const size_t OFF_H     = 67108864;
  const size_t OFF_W1B   = 134217728;
  const size_t OFF_W2B   = 134742016;
  const size_t OFF_BWB   = 135266304;
  const size_t OFF_HZWB  = 135364608;
  const size_t OFF_OUTWB = 135626752;
  const size_t OFF_HSB   = 135757824;
  const size_t OFF_HH1B  = 136282112;
  const size_t OFF_HH2   = 136806400;
  const size_t OFF_STATS = 137330688;
  const size_t OFF_SMMAX = 137334784;
  const size_t OFF_SMSUM = 137338880;

  unsigned short* xres  = (unsigned short*)(ws + OFF_XRES);
  unsigned short* xf    = (unsigned short*)(ws + OFF_XF);
  unsigned short* xfT   = (unsigned short*)(ws + OFF_XFT);
  unsigned short* bcc   = (unsigned short*)(ws + OFF_BCC);
  unsigned short* bcraw = (unsigned short*)(ws + OFF_BCRAW);
  unsigned short* ab    = (unsigned short*)(ws + OFF_AB);
  unsigned short* cmt   = (unsigned short*)(ws + OFF_CMT);
  float* hpart = (float*)(ws + OFF_HPART);
  unsigned short* x3T  = (unsigned short*)(ws + OFF_X3T);
  unsigned short* Hbuf = (unsigned short*)(ws + OFF_H);
  unsigned short* w1b = (unsigned short*)(ws + OFF_W1B);
  unsigned short* w2b = (unsigned short*)(ws + OFF_W2B);
  unsigned short* bwb = (unsigned short*)(ws + OFF_BWB);
  unsigned short* hzwb  = (unsigned short*)(ws + OFF_HZWB);
  unsigned short* outwb = (unsigned short*)(ws + OFF_OUTWB);
  unsigned short* hsb  = (unsigned short*)(ws + OFF_HSB);
  unsigned short* hh1b = (unsigned short*)(ws + OFF_HH1B);
  unsigned short* hh2  = (unsigned short*)(ws + OFF_HH2);
  float* bn1sum = (float*)(ws + OFF_STATS);
  float* bn1sq  = bn1sum + 256;
  float* bn2sum = bn1sum + 512;
  float* bn2sq  = bn1sum + 768;
  float* smmax = (float*)(ws + OFF_SMMAX);
  float* smsum = (float*)(ws + OFF_SMSUM);

  hipMemsetAsync(ws + OFF_STATS, 0, 4096, stream);
  k_setup<<<1024, 256, 0, stream>>>(ffn_w1, ffn_w2, bcdt_w, hz_w, out_w,
                                    w1b, w2b, bwb, hzwb, outwb);
  // stage 1: x1 = blend(x, BN(conv(x))), into xres (bf16)
  k_conv_stats<<<4096, 256, 0, stream>>>(x, dw1_w, bn1sum, bn1sq);
  k_conv_bn_blend_f2h<<<4096, 256, 0, stream>>>(x, dw1_w, bn1sum, bn1sq,
                                                bn1_g, bn1_b, alpha + 0, xres);
  // LN -> xf/xfT bf16
  k_ln<<<1024, 256, 0, stream>>>(xres, ln_w, ln_b, xf, xfT);
  // mixer
  k_bcdt<<<1024, 256, 0, stream>>>(xfT, bwb, bcdt_b, bcraw);
  k_conv_mid<<<3072, 256, 0, stream>>>(bcraw, mdw_w, mdw_b, bcc, smmax, smsum);
  k_ab_cmt<<<2048, 256, 0, stream>>>(bcc, smmax, smsum, ab, cmt);
  k_h<<<256, 512, 0, stream>>>(ab, xf, hpart);
  k_hsum<<<1024, 256, 0, stream>>>(hpart, hsb);
  k_hz<<<64, 256, 0, stream>>>(hsb, hzwb, hz_b, Dvec, hh1b);
  k_out<<<64, 256, 0, stream>>>(hh1b, outwb, out_b, hh2);
  k_y_blend<<<1024, 256, 0, stream>>>(hh2, cmt, alpha + 256, xres);
  // stage 2: x3 = blend(x2, BN2(conv2(x2))), in-place on xres (bf16)
  k_conv_stats_h<<<4096, 256, 0, stream>>>(xres, dw2_w, bn2sum, bn2sq);
  k_conv_bn_blend_h2h<<<4096, 256, 0, stream>>>(xres, dw2_w, bn2sum, bn2sq,
                                                bn2_g, bn2_b, alpha + 512, xres);
  // x3 -> x3T bf16
  k_xt<<<1024, 256, 0, stream>>>(xres, x3T);
  // FFN in two batch-halves; ffn2 writes d_out fp32 (blend with bf16 x3)
  k_ffn1<<<2048, 256, 0, stream>>>(x3T, w1b, ffn_b1, Hbuf, 0);
  k_ffn2<<<1024, 256, 0, stream>>>(Hbuf, w2b, ffn_b2, alpha + 768, xres, out, 0);
  k_ffn1<<<2048, 256, 0, stream>>>(x3T, w1b, ffn_b1, Hbuf, 8);
  k_ffn2<<<1024, 256, 0, stream>>>(Hbuf, w2b, ffn_b2, alpha + 768, xres, out, 8);
}